// Round 8
// baseline (7575.114 us; speedup 1.0000x reference)
//
#include <hip/hip_runtime.h>

#define DEV static __device__ __forceinline__

typedef _Float16 h2 __attribute__((ext_vector_type(2)));

DEV float fdot2f(h2 a, h2 b, float c) {
#if __has_builtin(__builtin_amdgcn_fdot2)
  return __builtin_amdgcn_fdot2(a, b, c, false);
#else
  return c + (float)a.x * (float)b.x + (float)a.y * (float)b.y;
#endif
}

// LayerNorm over 3 elements: (x-m)/sqrt(v+eps)*g + b
DEV void ln3(float& a, float& b, float& c, const float* g, const float* bt) {
  float m = (a + b + c) * (1.0f / 3.0f);
  float d0 = a - m, d1 = b - m, d2 = c - m;
  float v = (d0 * d0 + d1 * d1 + d2 * d2) * (1.0f / 3.0f);
  float rs = rsqrtf(v + 1e-5f);
  a = fmaf(d0 * rs, g[0], bt[0]);
  b = fmaf(d1 * rs, g[1], bt[1]);
  c = fmaf(d2 * rs, g[2], bt[2]);
}

DEV unsigned pkh2(float a, float b) {
  h2 v = {(_Float16)a, (_Float16)b};
  return __builtin_bit_cast(unsigned, v);
}

// ---------------------------------------------------------------------------
// Prepack:
//  FAB[l] = 2048 x uint4 contiguous per layer:
//    [0..1023]    { pk(w1[2jp][d],w1[2jp+1][d]) d=0..2, pk(b1 pair) }
//    [1024..2047] { pk(w2[d][2jp],w2[d][2jp+1]) d=0..2, 0 }
//  SM[l][128] fp32 attn/LN scalars at float offset 196608 | GLOB[16] after
// ---------------------------------------------------------------------------
__global__ void __launch_bounds__(256) prepack_kernel(
    const float* ea_w, const float* ea_b, const float* ea_ow, const float* ea_ob,
    const float* el1g, const float* el1b, const float* el2g, const float* el2b,
    const float* ef1w, const float* ef1b, const float* ef2w, const float* ef2b,
    const float* eng, const float* enb,
    const float* dsw, const float* dsb, const float* dsow, const float* dsob,
    const float* dcw, const float* dcb, const float* dcow, const float* dcob,
    const float* dl1g, const float* dl1b, const float* dl2g, const float* dl2b,
    const float* dl3g, const float* dl3b,
    const float* df1w, const float* df1b, const float* df2w, const float* df2b,
    const float* dng, const float* dnb,
    float* ws) {
  const int l = blockIdx.x, tid = threadIdx.x;
  const bool enc = l < 12;
  const int li = enc ? l : l - 12;
  const float* f1w = (enc ? ef1w : df1w) + li * 2048 * 3;
  const float* f1b = (enc ? ef1b : df1b) + li * 2048;
  const float* f2w = (enc ? ef2w : df2w) + li * 3 * 2048;
  uint4* FA4 = (uint4*)ws + (size_t)l * 2048;
  uint4* FB4 = FA4 + 1024;
  for (int jp = tid; jp < 1024; jp += 256) {
    const int j0 = jp * 2, j1 = j0 + 1;
    uint4 A;
    A.x = pkh2(f1w[j0 * 3 + 0], f1w[j1 * 3 + 0]);
    A.y = pkh2(f1w[j0 * 3 + 1], f1w[j1 * 3 + 1]);
    A.z = pkh2(f1w[j0 * 3 + 2], f1w[j1 * 3 + 2]);
    A.w = pkh2(f1b[j0], f1b[j1]);
    FA4[jp] = A;
    uint4 Bv;
    Bv.x = pkh2(f2w[j0], f2w[j1]);
    Bv.y = pkh2(f2w[2048 + j0], f2w[2048 + j1]);
    Bv.z = pkh2(f2w[4096 + j0], f2w[4096 + j1]);
    Bv.w = 0u;
    FB4[jp] = Bv;
  }
  float* S = ws + 196608 + l * 128;
  if (tid == 0) {
    // 0-26 qkv W | 27-35 qkv b | 36-44 ow | 45-47 ob | 48-53 ln1 g,b
    // 54-59 ln2 g,b | 60-62 ffn b2
    const float* aw = (enc ? ea_w : dsw) + li * 27;
    const float* ab = (enc ? ea_b : dsb) + li * 9;
    const float* aow = (enc ? ea_ow : dsow) + li * 9;
    const float* aob = (enc ? ea_ob : dsob) + li * 3;
    for (int i = 0; i < 27; ++i) S[i] = aw[i];
    for (int i = 0; i < 9; ++i) S[27 + i] = ab[i];
    for (int i = 0; i < 9; ++i) S[36 + i] = aow[i];
    for (int i = 0; i < 3; ++i) S[45 + i] = aob[i];
    const float* p;
    p = (enc ? el1g : dl1g) + li * 3; for (int i = 0; i < 3; ++i) S[48 + i] = p[i];
    p = (enc ? el1b : dl1b) + li * 3; for (int i = 0; i < 3; ++i) S[51 + i] = p[i];
    p = (enc ? el2g : dl2g) + li * 3; for (int i = 0; i < 3; ++i) S[54 + i] = p[i];
    p = (enc ? el2b : dl2b) + li * 3; for (int i = 0; i < 3; ++i) S[57 + i] = p[i];
    p = (enc ? ef2b : df2b) + li * 3; for (int i = 0; i < 3; ++i) S[60 + i] = p[i];
    if (!enc) {
      // 64-72 cross qW | 73-75 qb | 76-84 cross ow | 85-87 ob | 88-93 ln3 g,b
      // 94-102 kW | 103-105 kb | 106-114 vW | 115-117 vb
      const float* cw = dcw + li * 27;
      for (int i = 0; i < 9; ++i) {
        S[64 + i] = cw[i];
        S[94 + i] = cw[9 + i];
        S[106 + i] = cw[18 + i];
      }
      const float* cb = dcb + li * 9;
      for (int i = 0; i < 3; ++i) {
        S[73 + i] = cb[i];
        S[103 + i] = cb[3 + i];
        S[115 + i] = cb[6 + i];
      }
      for (int i = 0; i < 9; ++i) S[76 + i] = dcow[li * 9 + i];
      for (int i = 0; i < 3; ++i) S[85 + i] = dcob[li * 3 + i];
      p = dl3g + li * 3; for (int i = 0; i < 3; ++i) S[88 + i] = p[i];
      p = dl3b + li * 3; for (int i = 0; i < 3; ++i) S[91 + i] = p[i];
    }
  }
  if (l == 0 && tid == 1) {
    float* G = ws + 196608 + 24 * 128;
    for (int i = 0; i < 3; ++i) {
      G[i] = eng[i]; G[3 + i] = enb[i];
      G[6 + i] = dng[i]; G[9 + i] = dnb[i];
    }
  }
}

// Packed-f16 FFN for NR rows (rows = wave + 8*i), weights streamed from L2.
template <int NR>
DEV void ffn_core(const uint4* FA,
                  const float (&X0)[8], const float (&X1)[8], const float (&X2)[8],
                  float (&acc)[8][3], int lane) {
  h2 xd0[NR], xd1[NR], xd2[NR];
#pragma unroll
  for (int i = 0; i < NR; ++i) {
    xd0[i] = h2{(_Float16)X0[i], (_Float16)X0[i]};
    xd1[i] = h2{(_Float16)X1[i], (_Float16)X1[i]};
    xd2[i] = h2{(_Float16)X2[i], (_Float16)X2[i]};
  }
#pragma unroll
  for (int i = 0; i < NR; ++i) { acc[i][0] = 0.f; acc[i][1] = 0.f; acc[i][2] = 0.f; }
  const h2 z = {(_Float16)0, (_Float16)0};
#pragma unroll 4
  for (int kk = 0; kk < 16; ++kk) {
    const int jp = lane + (kk << 6);
    uint4 a = FA[jp];
    uint4 c = FA[1024 + jp];
    h2 wa0 = __builtin_bit_cast(h2, a.x), wa1 = __builtin_bit_cast(h2, a.y);
    h2 wa2 = __builtin_bit_cast(h2, a.z), bb = __builtin_bit_cast(h2, a.w);
    h2 wc0 = __builtin_bit_cast(h2, c.x), wc1 = __builtin_bit_cast(h2, c.y);
    h2 wc2 = __builtin_bit_cast(h2, c.z);
#pragma unroll
    for (int i = 0; i < NR; ++i) {
      h2 t = wa0 * xd0[i] + wa1 * xd1[i] + wa2 * xd2[i] + bb;
      t = __builtin_elementwise_max(t, z);
      acc[i][0] = fdot2f(wc0, t, acc[i][0]);
      acc[i][1] = fdot2f(wc1, t, acc[i][1]);
      acc[i][2] = fdot2f(wc2, t, acc[i][2]);
    }
  }
#pragma unroll
  for (int m = 1; m < 64; m <<= 1) {
#pragma unroll
    for (int i = 0; i < NR; ++i) {
      acc[i][0] += __shfl_xor(acc[i][0], m, 64);
      acc[i][1] += __shfl_xor(acc[i][1], m, 64);
      acc[i][2] += __shfl_xor(acc[i][2], m, 64);
    }
  }
}

// ---------------------------------------------------------------------------
// One layer. Phases (DEC, 5 barriers): P1 qkv | P2 self all-head partials
// (4 waves, b128 K/V) | P3 redundant C1 + cross partials (4 waves) |
// P3b X-combine (wave 0) | P4 8-wave FFN. ENC (4 barriers): P1|P2|P2b|P4.
// Partials transposed p*t[24][64] for coalesced combine reads.
// ---------------------------------------------------------------------------
template <bool DEC>
DEV void run_layer(const float* sm, const uint4* FA, const float4* ckv4,
                   float (*h)[5], float (*hln)[5], float (*xs)[5],
                   float (*kq)[5], float4* kvk, float4* kvv,
                   float (*p1t)[64], float (*p2t)[64],
                   float (*o_s)[5], const float* glob,
                   int R, int t, bool from_os, bool wpred,
                   int wave, int lane, int tid) {
  // ---- P1: QKV; thread (r,o) computes one projection output ----
  {
    const int r = tid >> 4, o = tid & 15;
    if (o < 9) {
      if (r < R) {
        float x0, x1, x2;
        if (DEC && from_os) {
          const bool real = r < t;  // rows >= t are the zero rep
          x0 = real ? o_s[r][0] : 0.f;
          x1 = real ? o_s[r][1] : 0.f;
          x2 = real ? o_s[r][2] : 0.f;
        } else {
          x0 = h[r][0]; x1 = h[r][1]; x2 = h[r][2];
        }
        float v = fmaf(sm[o * 3], x0,
                  fmaf(sm[o * 3 + 1], x1, fmaf(sm[o * 3 + 2], x2, sm[27 + o])));
        if (o < 3) kq[r][o] = v;
        else if (o < 6) ((float*)&kvk[r])[o - 3] = v;
        else ((float*)&kvv[r])[o - 6] = v;
      } else if (DEC) {  // pad rows: deterministic zeros (no NaN paths)
        if (o < 3) kq[r][o] = 0.f;
        else if (o < 6) ((float*)&kvk[r])[o - 3] = 0.f;
        else ((float*)&kvv[r])[o - 6] = 0.f;
      }
    } else if (o == 9) {
      if (DEC)
        ((float*)&kvk[r])[3] =
            (r == R - 1 && t > 0) ? (float)(64 - t) : (r < R ? 1.f : 0.f);
      if (DEC && from_os && r < R) {  // publish residual-stream input
        const bool real = r < t;
        h[r][0] = real ? o_s[r][0] : 0.f;
        h[r][1] = real ? o_s[r][1] : 0.f;
        h[r][2] = real ? o_s[r][2] : 0.f;
      }
    }
  }
  __syncthreads();
  // ---- P2: self-attn partials; 4 waves x 16 keys x all heads ----
  if (wave < 4) {
    const float l2e = 1.44269504f;
    float q0 = kq[lane][0] * l2e, q1 = kq[lane][1] * l2e, q2 = kq[lane][2] * l2e;
    float d0 = 0.f, n0 = 0.f, d1 = 0.f, n1 = 0.f, d2 = 0.f, n2 = 0.f;
    const int p0 = wave * 16;
#pragma unroll
    for (int pp = 0; pp < 16; ++pp) {
      float4 k = kvk[p0 + pp], v = kvv[p0 + pp];
      float e0 = exp2f(q0 * k.x), e1 = exp2f(q1 * k.y), e2 = exp2f(q2 * k.z);
      if (DEC) { e0 *= k.w; e1 *= k.w; e2 *= k.w; }
      d0 += e0; n0 = fmaf(e0, v.x, n0);
      d1 += e1; n1 = fmaf(e1, v.y, n1);
      d2 += e2; n2 = fmaf(e2, v.z, n2);
    }
    p1t[wave * 6 + 0][lane] = d0; p1t[wave * 6 + 1][lane] = n0;
    p1t[wave * 6 + 2][lane] = d1; p1t[wave * 6 + 3][lane] = n1;
    p1t[wave * 6 + 4][lane] = d2; p1t[wave * 6 + 5][lane] = n2;
  }
  __syncthreads();
  if (DEC) {
    // ---- P3: redundant C1 (lane=row) + cross-q + cross partials ----
    if (wave < 4) {
      float d0 = p1t[0][lane] + p1t[6][lane] + p1t[12][lane] + p1t[18][lane];
      float n0 = p1t[1][lane] + p1t[7][lane] + p1t[13][lane] + p1t[19][lane];
      float d1 = p1t[2][lane] + p1t[8][lane] + p1t[14][lane] + p1t[20][lane];
      float n1 = p1t[3][lane] + p1t[9][lane] + p1t[15][lane] + p1t[21][lane];
      float d2 = p1t[4][lane] + p1t[10][lane] + p1t[16][lane] + p1t[22][lane];
      float n2 = p1t[5][lane] + p1t[11][lane] + p1t[17][lane] + p1t[23][lane];
      float oh0 = __fdividef(n0, d0), oh1 = __fdividef(n1, d1), oh2 = __fdividef(n2, d2);
      float a0 = fmaf(sm[36], oh0, fmaf(sm[37], oh1, fmaf(sm[38], oh2, sm[45]))) + h[lane][0];
      float a1 = fmaf(sm[39], oh0, fmaf(sm[40], oh1, fmaf(sm[41], oh2, sm[46]))) + h[lane][1];
      float a2 = fmaf(sm[42], oh0, fmaf(sm[43], oh1, fmaf(sm[44], oh2, sm[47]))) + h[lane][2];
      ln3(a0, a1, a2, sm + 48, sm + 51);
      if (wave == 0 && lane < R) {
        hln[lane][0] = a0; hln[lane][1] = a1; hln[lane][2] = a2;
      }
      const float l2e = 1.44269504f;
      float q0 = fmaf(sm[64], a0, fmaf(sm[65], a1, fmaf(sm[66], a2, sm[73]))) * l2e;
      float q1 = fmaf(sm[67], a0, fmaf(sm[68], a1, fmaf(sm[69], a2, sm[74]))) * l2e;
      float q2 = fmaf(sm[70], a0, fmaf(sm[71], a1, fmaf(sm[72], a2, sm[75]))) * l2e;
      float D0 = 0.f, N0 = 0.f, D1 = 0.f, N1 = 0.f, D2 = 0.f, N2 = 0.f;
      const int p0 = wave * 16;
#pragma unroll
      for (int pp = 0; pp < 16; ++pp) {
        float4 k = ckv4[(p0 + pp) * 2], v = ckv4[(p0 + pp) * 2 + 1];
        float e0 = exp2f(q0 * k.x), e1 = exp2f(q1 * k.y), e2 = exp2f(q2 * k.z);
        D0 += e0; N0 = fmaf(e0, v.x, N0);
        D1 += e1; N1 = fmaf(e1, v.y, N1);
        D2 += e2; N2 = fmaf(e2, v.z, N2);
      }
      p2t[wave * 6 + 0][lane] = D0; p2t[wave * 6 + 1][lane] = N0;
      p2t[wave * 6 + 2][lane] = D1; p2t[wave * 6 + 3][lane] = N1;
      p2t[wave * 6 + 4][lane] = D2; p2t[wave * 6 + 5][lane] = N2;
    }
    __syncthreads();
  }
  // ---- P3b/P2b: X-combine (wave 0, lane=row) -> xs ----
  if (wave == 0) {
    const float (*pt)[64] = DEC ? p2t : p1t;
    float d0 = pt[0][lane] + pt[6][lane] + pt[12][lane] + pt[18][lane];
    float n0 = pt[1][lane] + pt[7][lane] + pt[13][lane] + pt[19][lane];
    float d1 = pt[2][lane] + pt[8][lane] + pt[14][lane] + pt[20][lane];
    float n1 = pt[3][lane] + pt[9][lane] + pt[15][lane] + pt[21][lane];
    float d2 = pt[4][lane] + pt[10][lane] + pt[16][lane] + pt[22][lane];
    float n2 = pt[5][lane] + pt[11][lane] + pt[17][lane] + pt[23][lane];
    float oh0 = __fdividef(n0, d0), oh1 = __fdividef(n1, d1), oh2 = __fdividef(n2, d2);
    const float* ow = DEC ? sm + 76 : sm + 36;
    const float* ob = DEC ? sm + 85 : sm + 45;
    float r0, r1, r2;
    if (DEC) { r0 = hln[lane][0]; r1 = hln[lane][1]; r2 = hln[lane][2]; }
    else     { r0 = h[lane][0];   r1 = h[lane][1];   r2 = h[lane][2]; }
    float a0 = fmaf(ow[0], oh0, fmaf(ow[1], oh1, fmaf(ow[2], oh2, ob[0]))) + r0;
    float a1 = fmaf(ow[3], oh0, fmaf(ow[4], oh1, fmaf(ow[5], oh2, ob[1]))) + r1;
    float a2 = fmaf(ow[6], oh0, fmaf(ow[7], oh1, fmaf(ow[8], oh2, ob[2]))) + r2;
    const float* lg = DEC ? sm + 54 : sm + 48;
    const float* lb = DEC ? sm + 57 : sm + 51;
    ln3(a0, a1, a2, lg, lb);
    if (lane < R) { xs[lane][0] = a0; xs[lane][1] = a1; xs[lane][2] = a2; }
  }
  __syncthreads();
  // ---- P4: FFN, 8 waves, rows = wave + 8*i (up to 8 rows/wave) ----
  {
    if (wave < 8 && wave < R) {
      const int nr = (R - wave + 7) >> 3;
      float X0[8], X1[8], X2[8];
#pragma unroll
      for (int i = 0; i < 8; ++i) {
        if (i < nr) {
          const int rc = wave + 8 * i;
          X0[i] = xs[rc][0]; X1[i] = xs[rc][1]; X2[i] = xs[rc][2];
        } else {
          X0[i] = 0.f; X1[i] = 0.f; X2[i] = 0.f;
        }
      }
      float acc[8][3];
      switch (nr) {
        case 1: ffn_core<1>(FA, X0, X1, X2, acc, lane); break;
        case 2: ffn_core<2>(FA, X0, X1, X2, acc, lane); break;
        case 3: ffn_core<3>(FA, X0, X1, X2, acc, lane); break;
        case 4: ffn_core<4>(FA, X0, X1, X2, acc, lane); break;
        case 5: ffn_core<5>(FA, X0, X1, X2, acc, lane); break;
        case 6: ffn_core<6>(FA, X0, X1, X2, acc, lane); break;
        case 7: ffn_core<7>(FA, X0, X1, X2, acc, lane); break;
        default: ffn_core<8>(FA, X0, X1, X2, acc, lane); break;
      }
      if (lane == 0) {
        const float* fg = DEC ? sm + 88 : sm + 54;
        const float* fb = DEC ? sm + 91 : sm + 57;
#pragma unroll
        for (int i = 0; i < 8; ++i) {
          if (i < nr) {
            const int r = wave + 8 * i;
            float y0 = acc[i][0] + sm[60] + X0[i];
            float y1 = acc[i][1] + sm[61] + X1[i];
            float y2 = acc[i][2] + sm[62] + X2[i];
            ln3(y0, y1, y2, fg, fb);
            h[r][0] = y0; h[r][1] = y1; h[r][2] = y2;
            if (DEC && wpred && r == R - 1) {  // pred[t] = dec_norm(zero-rep)
              ln3(y0, y1, y2, glob + 6, glob + 9);
              o_s[t][0] = y0; o_s[t][1] = y1; o_s[t][2] = y2;
            }
          }
        }
      }
    }
    __syncthreads();
  }
}

// ---------------------------------------------------------------------------
// Main kernel: one block per batch element. Encoder -> cross K/V precompute
// -> 63 autoregressive decode steps with zero-row dedup -> output transpose.
// ---------------------------------------------------------------------------
__global__ void __launch_bounds__(1024) tf_kernel(const float* src, const float* angle,
                                                  const float* ws, float* out) {
  __shared__ float small_s[24][128];
  __shared__ float glob[16];
  __shared__ float h[64][5];
  __shared__ float hln[64][5];
  __shared__ float xs[64][5];
  __shared__ float o_s[64][5];
  __shared__ float kq[64][5];
  __shared__ __align__(16) float4 kvk[64];
  __shared__ __align__(16) float4 kvv[64];
  __shared__ float p1t[24][64];
  __shared__ float p2t[24][64];
  __shared__ __align__(16) float ckcv[12][64][8];
  const int b = blockIdx.x;
  const int tid = threadIdx.x, wave = tid >> 6, lane = tid & 63;
  const uint4* FABg = (const uint4*)ws;
  const float* SM = ws + 196608;
  const float* GB = SM + 24 * 128;
  for (int i = tid; i < 24 * 128; i += 1024) ((float*)small_s)[i] = SM[i];
  if (tid < 16) glob[tid] = GB[tid];
  if (tid < 64) {
    float x0 = src[b * 128 + tid];
    float x1 = src[b * 128 + 64 + tid];
    float x2 = angle[b];
    h[tid][0] = x0; h[tid][1] = x1; h[tid][2] = x2;
    o_s[tid][0] = (tid == 0) ? x0 : 0.f;
    o_s[tid][1] = (tid == 0) ? x1 : 0.f;
    o_s[tid][2] = (tid == 0) ? x2 : 0.f;
  }
  __syncthreads();
  // ---- encoder (R=64) ----
  for (int l = 0; l < 12; ++l)
    run_layer<false>(small_s[l], FABg + (size_t)l * 2048, nullptr,
                     h, hln, xs, kq, kvk, kvv, p1t, p2t, o_s, glob,
                     64, 0, false, false, wave, lane, tid);
  // final encoder LN -> mem (in place in h)
  if (tid < 64) {
    float a = h[tid][0], bb = h[tid][1], c = h[tid][2];
    ln3(a, bb, c, glob + 0, glob + 3);
    h[tid][0] = a; h[tid][1] = bb; h[tid][2] = c;
  }
  __syncthreads();
  // ---- precompute cross-attn K/V per decoder layer (k at [0..2], v at [4..6]) ----
  if (wave < 12) {
    const float* sm = small_s[12 + wave];
    float m0 = h[lane][0], m1 = h[lane][1], m2 = h[lane][2];
    float k0 = fmaf(sm[94], m0, fmaf(sm[95], m1, fmaf(sm[96], m2, sm[103])));
    float k1 = fmaf(sm[97], m0, fmaf(sm[98], m1, fmaf(sm[99], m2, sm[104])));
    float k2 = fmaf(sm[100], m0, fmaf(sm[101], m1, fmaf(sm[102], m2, sm[105])));
    float v0 = fmaf(sm[106], m0, fmaf(sm[107], m1, fmaf(sm[108], m2, sm[115])));
    float v1 = fmaf(sm[109], m0, fmaf(sm[110], m1, fmaf(sm[111], m2, sm[116])));
    float v2 = fmaf(sm[112], m0, fmaf(sm[113], m1, fmaf(sm[114], m2, sm[117])));
    ckcv[wave][lane][0] = k0; ckcv[wave][lane][1] = k1; ckcv[wave][lane][2] = k2;
    ckcv[wave][lane][3] = 0.f;
    ckcv[wave][lane][4] = v0; ckcv[wave][lane][5] = v1; ckcv[wave][lane][6] = v2;
    ckcv[wave][lane][7] = 0.f;
  }
  __syncthreads();
  // ---- autoregressive decode: step t fills o_s[t] ----
  for (int t = 1; t < 64; ++t) {
    const int R = t + 1;
    for (int li = 0; li < 12; ++li)
      run_layer<true>(small_s[12 + li], FABg + (size_t)(12 + li) * 2048,
                      (const float4*)ckcv[li],
                      h, hln, xs, kq, kvk, kvv, p1t, p2t, o_s, glob, R, t,
                      /*from_os=*/li == 0, /*wpred=*/li == 11, wave, lane, tid);
  }
  // ---- output: [B,3,T] ----
  if (tid < 192) {
    int d = tid / 64, tt = tid % 64;
    out[b * 192 + tid] = o_s[tt][d];
  }
}

extern "C" void kernel_launch(void* const* d_in, const int* in_sizes, int n_in,
                              void* d_out, int out_size, void* d_ws, size_t ws_size,
                              hipStream_t stream) {
  (void)in_sizes; (void)n_in; (void)out_size; (void)ws_size;
  float* ws = (float*)d_ws;
  prepack_kernel<<<24, 256, 0, stream>>>(
      (const float*)d_in[2], (const float*)d_in[3], (const float*)d_in[4], (const float*)d_in[5],
      (const float*)d_in[6], (const float*)d_in[7], (const float*)d_in[8], (const float*)d_in[9],
      (const float*)d_in[10], (const float*)d_in[11], (const float*)d_in[12], (const float*)d_in[13],
      (const float*)d_in[14], (const float*)d_in[15],
      (const float*)d_in[16], (const float*)d_in[17], (const float*)d_in[18], (const float*)d_in[19],
      (const float*)d_in[20], (const float*)d_in[21], (const float*)d_in[22], (const float*)d_in[23],
      (const float*)d_in[24], (const float*)d_in[25], (const float*)d_in[26], (const float*)d_in[27],
      (const float*)d_in[28], (const float*)d_in[29],
      (const float*)d_in[30], (const float*)d_in[31], (const float*)d_in[32], (const float*)d_in[33],
      (const float*)d_in[34], (const float*)d_in[35],
      ws);
  tf_kernel<<<32, 1024, 0, stream>>>((const float*)d_in[0], (const float*)d_in[1], ws,
                                     (float*)d_out);
}